// Round 9
// baseline (336.411 us; speedup 1.0000x reference)
//
#include <hip/hip_runtime.h>
#include <stdint.h>

#define B_ 4
#define S_ 1024
#define HID_ 1024
#define H_ 16
#define DH_ 64
#define NDIST 33
#define SCALE_ 0.125f

typedef unsigned short u16;
typedef __attribute__((ext_vector_type(8))) short short8;
typedef __attribute__((ext_vector_type(4))) float floatx4;

static __device__ __forceinline__ float bf2f(u16 u) {
  union { unsigned int i; float f; } v; v.i = ((unsigned int)u) << 16; return v.f;
}
static __device__ __forceinline__ u16 f2bf(float x) {
  union { float f; unsigned int i; } v; v.f = x;
  return (u16)((v.i + 0x7FFFu + ((v.i >> 16) & 1u)) >> 16);
}
static __device__ __forceinline__ floatx4 mfma_bf16(short8 a, short8 b, floatx4 c) {
  return __builtin_amdgcn_mfma_f32_16x16x32_bf16(a, b, c, 0, 0, 0);
}
// async global->LDS, 16B per lane. LDS dest = wave-uniform base + lane*16;
// global src is per-lane (m97/m104 verified pattern).
static __device__ __forceinline__ void gload_lds16(const void* g, void* l) {
  __builtin_amdgcn_global_load_lds(
      (const __attribute__((address_space(1))) unsigned int*)g,
      (__attribute__((address_space(3))) unsigned int*)l, 16, 0, 0);
}

// conv region element offsets (u16 units)
#define OFF_BQ   0
#define OFF_BK   1024
#define OFF_BV   2048
#define OFF_RELK 3072
#define OFF_RELV 5184
#define OFF_FCW  7296
#define OFF_FCB  1055872
#define CONV_TOT 1056896

struct SrcPtrs { const void* p[7]; };

// ---------------------------------------------------------------------------
// Dtype detector: fp32 read as u16 pairs -> even halves are mantissa bits ->
// huge as bf16. flag=1 means fp32 inputs.
// ---------------------------------------------------------------------------
__global__ __launch_bounds__(256) void detect_kernel(const u16* __restrict__ q,
                                                     int* __restrict__ flag) {
  __shared__ float red[256];
  float m = 0.f;
  for (int i = threadIdx.x; i < 8192; i += 256) {
    float v = fabsf(bf2f(q[2 * i]));
    m = fmaxf(m, (v < 1e30f) ? v : 1e20f);
  }
  red[threadIdx.x] = m;
  __syncthreads();
  for (int s = 128; s > 0; s >>= 1) {
    if (threadIdx.x < (unsigned)s) red[threadIdx.x] = fmaxf(red[threadIdx.x], red[threadIdx.x + s]);
    __syncthreads();
  }
  if (threadIdx.x == 0) *flag = (red[0] > 1e4f) ? 1 : 0;
}

// ---------------------------------------------------------------------------
// Convert biases / rel tables / fcW to bf16 (copy if already bf16).
// ---------------------------------------------------------------------------
__global__ __launch_bounds__(256) void convert_kernel(SrcPtrs srcs,
                                                      const int* __restrict__ flag,
                                                      u16* __restrict__ dst) {
  constexpr int segsz[7] = {1024,1024,1024,2112,2112,1048576,1024};
  constexpr int cumE[7]  = {OFF_BQ,OFF_BK,OFF_BV,OFF_RELK,OFF_RELV,OFF_FCW,OFF_FCB};
  constexpr int cumB[8]  = {0,1,2,3,6,9,1033,1034};
  const int bid = blockIdx.x;
  int t = 0;
  #pragma unroll
  for (int i = 1; i < 7; ++i) if (bid >= cumB[i]) t = i;
  const int chunk = (bid - cumB[t]) * 1024 + threadIdx.x * 4;
  if (chunk >= segsz[t]) return;
  __align__(8) u16 o[4];
  if (*flag) {
    const float* s = (const float*)srcs.p[t];
    float4 v = *(const float4*)(s + chunk);
    o[0] = f2bf(v.x); o[1] = f2bf(v.y); o[2] = f2bf(v.z); o[3] = f2bf(v.w);
  } else {
    const u16* s = (const u16*)srcs.p[t];
    *(uint2*)o = *(const uint2*)(s + chunk);
  }
  *(uint2*)(dst + cumE[t] + chunk) = *(const uint2*)o;
}

// ---------------------------------------------------------------------------
// Q/K/V input -> bf16 (copy if already bf16). 3 x [4096][1024], 8 elems/thr,
// grid-stride. Same f2bf as the old in-proj convert -> bit-identical values.
// ---------------------------------------------------------------------------
__global__ __launch_bounds__(256) void qkvconv_kernel(
    const void* __restrict__ qin, const void* __restrict__ kin,
    const void* __restrict__ vin, const int* __restrict__ flag,
    u16* __restrict__ qc, u16* __restrict__ kc, u16* __restrict__ vc)
{
  const int isf = *flag;
  const int total = 3 * (4096 * 1024 / 8);          // 1,572,864 groups
  for (int g = blockIdx.x * 256 + threadIdx.x; g < total; g += gridDim.x * 256) {
    const int z = g >> 19;                          // 524288 groups per tensor
    const int off = (g & 524287) * 8;
    const void* src = (z == 0) ? qin : (z == 1) ? kin : vin;
    u16* dst = (z == 0) ? qc : (z == 1) ? kc : vc;
    if (isf) {
      const float* s = (const float*)src + off;
      float4 v0 = *(const float4*)s;
      float4 v1 = *(const float4*)(s + 4);
      __align__(16) u16 tmp[8] = {f2bf(v0.x),f2bf(v0.y),f2bf(v0.z),f2bf(v0.w),
                                  f2bf(v1.x),f2bf(v1.y),f2bf(v1.z),f2bf(v1.w)};
      *(uint4*)(dst + off) = *(const uint4*)tmp;
    } else {
      *(uint4*)(dst + off) = *(const uint4*)((const u16*)src + off);
    }
  }
}

// ---------------------------------------------------------------------------
// W transpose: raw W [h][d][e] (fp32 or bf16) -> wt[z][h*64+e][d] bf16.
// grid (16 d-tiles, 16 h, 3 z), block 256.
// ---------------------------------------------------------------------------
__global__ __launch_bounds__(256) void wtrans_kernel(
    const void* __restrict__ Wq, const void* __restrict__ Wk, const void* __restrict__ Wv,
    const int* __restrict__ flag, u16* __restrict__ wt)
{
  const int dt = blockIdx.x, h = blockIdx.y, z = blockIdx.z;
  const void* W = (z == 0) ? Wq : (z == 1) ? Wk : Wv;
  const int tid = threadIdx.x;
  const int isf = *flag;
  __shared__ __align__(16) u16 t_l[64 * 72];

  #pragma unroll
  for (int i = 0; i < 2; ++i) {
    int g = tid + 256 * i;
    int d = g & 63, e8 = (g >> 6) * 8;
    size_t off = ((size_t)h * HID_ + dt * 64 + d) * DH_ + e8;
    __align__(16) u16 tmp[8];
    if (isf) {
      const float* Wf = (const float*)W + off;
      float4 v0 = *(const float4*)Wf;
      float4 v1 = *(const float4*)(Wf + 4);
      tmp[0]=f2bf(v0.x); tmp[1]=f2bf(v0.y); tmp[2]=f2bf(v0.z); tmp[3]=f2bf(v0.w);
      tmp[4]=f2bf(v1.x); tmp[5]=f2bf(v1.y); tmp[6]=f2bf(v1.z); tmp[7]=f2bf(v1.w);
    } else {
      *(uint4*)tmp = *(const uint4*)((const u16*)W + off);
    }
    #pragma unroll
    for (int j = 0; j < 8; ++j) {
      int e = e8 + j;
      t_l[e * 72 + (((d >> 3) ^ (e & 7)) << 3) + (d & 7)] = tmp[j];
    }
  }
  __syncthreads();
  {
    int e = tid >> 2, c0 = (tid & 3) * 2;
    u16* dst = wt + ((size_t)(z * H_ + h) * DH_ + e) * HID_ + dt * 64;
    uint4 x0 = *(const uint4*)(t_l + e * 72 + (((c0    ) ^ (e & 7)) << 3));
    uint4 x1 = *(const uint4*)(t_l + e * 72 + (((c0 + 1) ^ (e & 7)) << 3));
    *(uint4*)(dst + c0 * 8)     = x0;
    *(uint4*)(dst + c0 * 8 + 8) = x1;
  }
}

// ---------------------------------------------------------------------------
// Q/K/V projection GEMM: [4096 x 1024] @ Wcat^T, 128x128 tile, BK=32.
// Double-buffered LDS, one barrier per K-step, pure global_load_lds staging,
// chunk-XOR swizzle (verified round 7). grid (32, 8, 3), block 256.
// ---------------------------------------------------------------------------
__global__ __launch_bounds__(256, 3) void proj_kernel(
    const u16* __restrict__ qc, const u16* __restrict__ kc, const u16* __restrict__ vc,
    const u16* __restrict__ wt, const u16* __restrict__ conv,
    u16* __restrict__ qo, u16* __restrict__ ko, u16* __restrict__ vo)
{
  const int z = blockIdx.z;
  const u16* A    = (z == 0) ? qc : (z == 1) ? kc : vc;
  const u16* Wz   = wt + (size_t)z * (H_ * DH_ * HID_);
  const u16* bias = conv + ((z == 0) ? OFF_BQ : (z == 1) ? OFF_BK : OFF_BV);
  u16*       O    = (z == 0) ? qo : (z == 1) ? ko : vo;
  const int rt = blockIdx.x, ct = blockIdx.y;
  const int tid = threadIdx.x, lane = tid & 63, w = tid >> 6, quad = lane >> 4, l16 = lane & 15;

  __shared__ __align__(16) u16 a_l[2][128 * 32];
  __shared__ __align__(16) u16 b_l[2][128 * 32];

  floatx4 acc[4][4];
  #pragma unroll
  for (int i = 0; i < 4; ++i)
    #pragma unroll
    for (int j = 0; j < 4; ++j) acc[i][j] = (floatx4){0.f,0.f,0.f,0.f};

  const int mq = (w & 1) * 64, nq = (w >> 1) * 64;
  const int u = (lane & 3) ^ ((lane >> 3) & 3);   // inverse-swizzled src chunk
  const int cs = (quad ^ ((l16 >> 1) & 3)) * 8;   // swizzled read chunk offset

  auto STAGE = [&](int bu, int kk) {
    #pragma unroll
    for (int i = 0; i < 2; ++i) {
      int row = (tid + 256 * i) >> 2;
      gload_lds16(A  + (size_t)(rt * 128 + row) * HID_ + kk * 32 + u * 8,
                  a_l[bu] + (w * 64 + i * 256) * 8);
      gload_lds16(Wz + (size_t)(ct * 128 + row) * HID_ + kk * 32 + u * 8,
                  b_l[bu] + (w * 64 + i * 256) * 8);
    }
  };

  STAGE(0, 0);
  int cur = 0;
  for (int kk = 0; kk < 32; ++kk) {
    __syncthreads();            // drains vmcnt -> buf[cur] complete; orders prev reads
    if (kk + 1 < 32) STAGE(cur ^ 1, kk + 1);
    const u16* ab = a_l[cur];
    const u16* bb = b_l[cur];
    short8 af[4], bfr[4];
    #pragma unroll
    for (int i = 0; i < 4; ++i) {
      af[i]  = *(const short8*)(ab + (mq + i * 16 + l16) * 32 + cs);
      bfr[i] = *(const short8*)(bb + (nq + i * 16 + l16) * 32 + cs);
    }
    #pragma unroll
    for (int i = 0; i < 4; ++i)
      #pragma unroll
      for (int j = 0; j < 4; ++j)
        acc[i][j] = mfma_bf16(af[i], bfr[j], acc[i][j]);
    cur ^= 1;
  }

  #pragma unroll
  for (int j = 0; j < 4; ++j) {
    int col = ct * 128 + nq + j * 16 + l16;
    int hh = col >> 6, e = col & 63;
    float bb = bf2f(bias[hh * 64 + e]);
    #pragma unroll
    for (int i = 0; i < 4; ++i) {
      #pragma unroll
      for (int r = 0; r < 4; ++r) {
        int m = rt * 128 + mq + i * 16 + quad * 4 + r;
        int bidx = m >> 10, srow = m & 1023;
        O[(((size_t)(bidx * H_ + hh)) * S_ + srow) * DH_ + e] = f2bf(acc[i][j][r] + bb);
      }
    }
  }
}

// ---------------------------------------------------------------------------
// Fused attention, q-tile 64 x k-tile 64, 16 k-steps, 2 barriers each.
// This revision = verified round-8 kernel + ONE change:
//  - near-path butterflies REMOVED. Every near element does one direct
//    atomicAdd(&bucket[m*33+dist], pv) (fire-and-forget ds_add_f32).
//    Correctness: interior dists (1..31) have exactly one global k per (m,d)
//    (k = m+d-16), so each is added once; end dists (0/32) accumulate via the
//    LDS atomic instead of a 4-step x 2-side x 4-row shfl butterfly + leader
//    atomic. Same sums, commutative f32 reassociation only. Cuts ~128 shfl
//    (ds_permute = LDS pipe) + butterfly VALU per thread per near step --
//    the near path was ~14x a far step's LDS-pipe cost, on the saturated pipe.
// grid (16, 16, 4), block 256.
// ---------------------------------------------------------------------------
__global__ __launch_bounds__(256, 4) void attn_kernel(
    const u16* __restrict__ Q, const u16* __restrict__ K, const u16* __restrict__ V,
    const u16* __restrict__ conv, u16* __restrict__ Ox)
{
  // XCD-aware bijective swizzle of the flat block id (1024 blocks, 8 XCDs)
  const int bid = blockIdx.x + 16 * (blockIdx.y + 16 * blockIdx.z);
  const int nid = (bid & 7) * 128 + (bid >> 3);
  const int qt = nid & 15, h = (nid >> 4) & 15, b = nid >> 8;

  const int tid = threadIdx.x;
  const int lane = tid & 63, w = tid >> 6, quad = lane >> 4, l16 = lane & 15;
  const size_t base = ((size_t)(b * H_ + h)) * S_ * DH_;
  const u16* Kb = K + base;
  const u16* Vb = V + base;

  __shared__ __align__(16) char smem[40320];
  u16*   p_l    = (u16*)(smem);            // [64][72]; preamble: Q tile; epilogue: Bfull
  u16*   q_l    = p_l;                     // alias (dead after preamble)
  u16*   k_l    = (u16*)(smem + 9216);     // [64][72]; epilogue: relv^T [64 e][72]
  u16*   vt_l   = (u16*)(smem + 18432);    // [64 e][72] plain V^T (row e, col k)
  u16*   rq_l   = (u16*)(smem + 27648);    // [64][33] bf16 (near tiles only)
  float* bucket = (float*)(smem + 31872);  // [64][33]; preamble: relk_b u16 [48][72]
  u16*   rkb    = (u16*)(smem + 31872);

  // issue kt=0 K/V loads immediately; the whole preamble covers their latency
  uint4 kr0 = *(const uint4*)(Kb + (size_t)(tid >> 3) * DH_ + (tid & 7) * 8);
  uint4 kr1 = *(const uint4*)(Kb + (size_t)((tid >> 3) + 32) * DH_ + (tid & 7) * 8);
  uint4 vr0 = *(const uint4*)(Vb + (size_t)lane * DH_ + w * 16);
  uint4 vr1 = *(const uint4*)(Vb + (size_t)lane * DH_ + w * 16 + 8);

  // preamble: stage Q tile + relk (B-layout rows, zero-padded to 48)
  #pragma unroll
  for (int i = 0; i < 2; ++i) {
    int idx = tid + 256 * i;
    int row = idx >> 3, c8 = (idx & 7) * 8;
    *(uint4*)(q_l + row * 72 + c8) =
        *(const uint4*)(Q + base + (size_t)(qt * 64 + row) * DH_ + c8);
  }
  const u16* relk = conv + OFF_RELK;
  for (int idx = tid; idx < 48 * 8; idx += 256) {
    int row = idx >> 3, c8 = (idx & 7) * 8;
    uint4 v = make_uint4(0, 0, 0, 0);
    if (row < NDIST) v = *(const uint4*)(relk + row * 64 + c8);
    *(uint4*)(rkb + row * 72 + c8) = v;
  }
  __syncthreads();

  const int m0 = w * 16;
  short8 qa0 = *(const short8*)(q_l + (m0 + l16) * 72 + quad * 8);
  short8 qa1 = *(const short8*)(q_l + (m0 + l16) * 72 + 32 + quad * 8);

  // RQ[m][d] = q[m,:] . relk[d,:]  (capture d=0 / d=32 accumulators)
  floatx4 c_d0 = {0.f,0.f,0.f,0.f}, c_d32 = {0.f,0.f,0.f,0.f};
  #pragma unroll
  for (int t3 = 0; t3 < 3; ++t3) {
    floatx4 c = {0.f,0.f,0.f,0.f};
    c = mfma_bf16(qa0, *(const short8*)(rkb + (t3 * 16 + l16) * 72 + quad * 8), c);
    c = mfma_bf16(qa1, *(const short8*)(rkb + (t3 * 16 + l16) * 72 + 32 + quad * 8), c);
    if (t3 == 0) c_d0 = c;
    if (t3 == 2) c_d32 = c;
    int d = t3 * 16 + l16;
    if (d < NDIST) {
      #pragma unroll
      for (int r = 0; r < 4; ++r) rq_l[(m0 + quad * 4 + r) * 33 + d] = f2bf(c[r]);
    }
  }
  // far-tile bias: RQ[m][0]/RQ[m][32] held by lane quad*16+0 (col=lane&15=0);
  // broadcast, apply the same bf16 round-trip, pre-scale.
  float rqs_lo[4], rqs_hi[4];
  #pragma unroll
  for (int r = 0; r < 4; ++r) {
    rqs_lo[r] = bf2f(f2bf(__shfl(c_d0[r],  lane & 48, 64))) * SCALE_;
    rqs_hi[r] = bf2f(f2bf(__shfl(c_d32[r], lane & 48, 64))) * SCALE_;
  }
  __syncthreads();              // relk_b/q_l reads done -> regions become bucket/p_l
  for (int idx = tid; idx < 64 * 33; idx += 256) bucket[idx] = 0.f;

  floatx4 o[4], oi = {0.f,0.f,0.f,0.f};
  #pragma unroll
  for (int t = 0; t < 4; ++t) o[t] = (floatx4){0.f,0.f,0.f,0.f};

  for (int kt = 0; kt < 16; ++kt) {
    __syncthreads();            // prev iter LDS reads done (kt=0: bucket zero visible)
    // write-late: staged registers -> LDS (vmcnt wait forced by reg dataflow)
    *(uint4*)(k_l + (tid >> 3) * 72 + (tid & 7) * 8) = kr0;
    *(uint4*)(k_l + ((tid >> 3) + 32) * 72 + (tid & 7) * 8) = kr1;
    {
      const u16* t8 = (const u16*)&vr0;
      #pragma unroll
      for (int j = 0; j < 8; ++j) vt_l[(w * 16 + j) * 72 + lane] = t8[j];
      const u16* t9 = (const u16*)&vr1;
      #pragma unroll
      for (int j = 0; j < 8; ++j) vt_l[(w * 16 + 8 + j) * 72 + lane] = t9[j];
    }
    __syncthreads();
    // issue-early: next tile's loads fly under the whole compute phase
    if (kt < 15) {
      const size_t kb = (size_t)((kt + 1) * 64);
      kr0 = *(const uint4*)(Kb + (kb + (tid >> 3)) * DH_ + (tid & 7) * 8);
      kr1 = *(const uint4*)(Kb + (kb + (tid >> 3) + 32) * DH_ + (tid & 7) * 8);
      vr0 = *(const uint4*)(Vb + (kb + lane) * DH_ + w * 16);
      vr1 = *(const uint4*)(Vb + (kb + lane) * DH_ + w * 16 + 8);
    }

    const int dkt = kt - qt;
    const bool near = (dkt >= -1) && (dkt <= 1);

    #pragma unroll
    for (int t = 0; t < 4; ++t) {
      floatx4 s = {0.f,0.f,0.f,0.f};
      s = mfma_bf16(qa0, *(const short8*)(k_l + (t * 16 + l16) * 72 + quad * 8), s);
      s = mfma_bf16(qa1, *(const short8*)(k_l + (t * 16 + l16) * 72 + 32 + quad * 8), s);
      int kcol = t * 16 + l16;
      if (near) {
        #pragma unroll
        for (int r = 0; r < 4; ++r) {
          int m = m0 + quad * 4 + r;
          int delta = (kt * 64 + kcol) - (qt * 64 + m);
          int dist = (delta < -16 ? -16 : (delta > 16 ? 16 : delta)) + 16;
          float logit = (s[r] + bf2f(rq_l[m * 33 + dist])) * SCALE_;
          u16 pu = f2bf(__expf(fminf(logit, 30.f)));
          p_l[m * 72 + kcol] = pu;
          atomicAdd(&bucket[m * 33 + dist], bf2f(pu));
        }
      } else {
        #pragma unroll
        for (int r = 0; r < 4; ++r) {
          int m = m0 + quad * 4 + r;
          float logit = fmaf(s[r], SCALE_, (dkt < 0) ? rqs_lo[r] : rqs_hi[r]);
          u16 pu = f2bf(__expf(fminf(logit, 30.f)));
          p_l[m * 72 + kcol] = pu;
        }
      }
    }

    // PV + far-tile indicator row-sums (same-wave P round-trip, no barrier)
    u16 iv = ((l16 == 0 && dkt <= -2) || (l16 == 1 && dkt >= 2)) ? (u16)0x3F80 : (u16)0;
    short8 ib;
    #pragma unroll
    for (int j = 0; j < 8; ++j) ib[j] = (short)iv;
    short8 pa0 = *(const short8*)(p_l + (m0 + l16) * 72 + quad * 8);
    short8 pa1 = *(const short8*)(p_l + (m0 + l16) * 72 + 32 + quad * 8);
    oi = mfma_bf16(pa0, ib, oi);
    oi = mfma_bf16(pa1, ib, oi);
    #pragma unroll
    for (int t = 0; t < 4; ++t) {
      int e = t * 16 + l16;
      short8 vb0 = *(const short8*)(vt_l + e * 72 + quad * 8);
      short8 vb1 = *(const short8*)(vt_l + e * 72 + 32 + quad * 8);
      o[t] = mfma_bf16(pa0, vb0, o[t]);
      o[t] = mfma_bf16(pa1, vb1, o[t]);
    }
  }

  __syncthreads();              // loop LDS use + atomics done
  // fold far sums (s_lo at col0, s_hi at col1 of oi) into bucket
  if (l16 == 0) {
    #pragma unroll
    for (int r = 0; r < 4; ++r) bucket[(m0 + quad * 4 + r) * 33 + 0] += oi[r];
  } else if (l16 == 1) {
    #pragma unroll
    for (int r = 0; r < 4; ++r) bucket[(m0 + quad * 4 + r) * 33 + 32] += oi[r];
  }
  __syncthreads();

  u16* rvT = k_l;               // relv^T [64 e][72]
  u16* Bf  = p_l;               // Bfull bf16 [64 m][72]
  for (int idx = tid; idx < 576; idx += 256) {
    ((uint4*)rvT)[idx] = make_uint4(0, 0, 0, 0);
    ((uint4*)Bf)[idx]  = make_uint4(0, 0, 0, 0);
  }
  __syncthreads();
  const u16* relv = conv + OFF_RELV;
  for (int idx = tid; idx < NDIST * 64; idx += 256) {
    int d = idx >> 6, e = idx & 63;
    rvT[e * 72 + d] = relv[idx];
  }
  for (int idx = tid; idx < 64 * NDIST; idx += 256) {
    int m = idx / NDIST, d = idx - m * NDIST;
    Bf[m * 72 + d] = f2bf(bucket[m * 33 + d]);
  }
  __syncthreads();

  // o += Bfull @ relv
  short8 ba0 = *(const short8*)(Bf + (m0 + l16) * 72 + quad * 8);
  short8 ba1 = *(const short8*)(Bf + (m0 + l16) * 72 + 32 + quad * 8);
  #pragma unroll
  for (int t = 0; t < 4; ++t) {
    short8 rb0 = *(const short8*)(rvT + (t * 16 + l16) * 72 + quad * 8);
    short8 rb1 = *(const short8*)(rvT + (t * 16 + l16) * 72 + 32 + quad * 8);
    o[t] = mfma_bf16(ba0, rb0, o[t]);
    o[t] = mfma_bf16(ba1, rb1, o[t]);
  }

  float rl[4];
  #pragma unroll
  for (int r = 0; r < 4; ++r) {
    int m = m0 + quad * 4 + r;
    float s = 0.f;
    #pragma unroll
    for (int d = 0; d < NDIST; ++d) s += bucket[m * 33 + d];
    rl[r] = 1.f / s;
  }

  #pragma unroll
  for (int t = 0; t < 4; ++t) {
    int e = t * 16 + l16;
    #pragma unroll
    for (int r = 0; r < 4; ++r) {
      int srow = qt * 64 + m0 + quad * 4 + r;
      Ox[((size_t)(b * S_ + srow)) * HID_ + h * 64 + e] = f2bf(o[t][r] * rl[r]);
    }
  }
}

// ---------------------------------------------------------------------------
// fc: out = X @ fcW^T + b. X bf16 [4096][1024] (ws), fcW k-contiguous.
// Same dbuf + 1-barrier + chunk-XOR-swizzle structure as proj. 128x128 tile,
// BK=32, grid (32, 8), block 256. Dual-dtype output.
// ---------------------------------------------------------------------------
__global__ __launch_bounds__(256, 3) void fc_kernel(
    const u16* __restrict__ X, const u16* __restrict__ conv,
    const int* __restrict__ flag, void* __restrict__ outv)
{
  const u16* Wf  = conv + OFF_FCW;
  const u16* bfc = conv + OFF_FCB;
  const int rt = blockIdx.x, ct = blockIdx.y;
  const int tid = threadIdx.x, lane = tid & 63, w = tid >> 6, quad = lane >> 4, l16 = lane & 15;
  const int isf = *flag;

  __shared__ __align__(16) u16 a_l[2][128 * 32];
  __shared__ __align__(16) u16 b_l[2][128 * 32];

  floatx4 acc[4][4];
  #pragma unroll
  for (int i = 0; i < 4; ++i)
    #pragma unroll
    for (int j = 0; j < 4; ++j) acc[i][j] = (floatx4){0.f,0.f,0.f,0.f};

  const int mq = (w & 1) * 64, nq = (w >> 1) * 64;
  const int u = (lane & 3) ^ ((lane >> 3) & 3);
  const int cs = (quad ^ ((l16 >> 1) & 3)) * 8;

  auto STAGE = [&](int bu, int kk) {
    #pragma unroll
    for (int i = 0; i < 2; ++i) {
      int row = (tid + 256 * i) >> 2;
      gload_lds16(X  + (size_t)(rt * 128 + row) * HID_ + kk * 32 + u * 8,
                  a_l[bu] + (w * 64 + i * 256) * 8);
      gload_lds16(Wf + (size_t)(ct * 128 + row) * HID_ + kk * 32 + u * 8,
                  b_l[bu] + (w * 64 + i * 256) * 8);
    }
  };

  STAGE(0, 0);
  int cur = 0;
  for (int kk = 0; kk < 32; ++kk) {
    __syncthreads();
    if (kk + 1 < 32) STAGE(cur ^ 1, kk + 1);
    const u16* ab = a_l[cur];
    const u16* bb = b_l[cur];
    short8 af[4], bfr[4];
    #pragma unroll
    for (int i = 0; i < 4; ++i) {
      af[i]  = *(const short8*)(ab + (mq + i * 16 + l16) * 32 + cs);
      bfr[i] = *(const short8*)(bb + (nq + i * 16 + l16) * 32 + cs);
    }
    #pragma unroll
    for (int i = 0; i < 4; ++i)
      #pragma unroll
      for (int j = 0; j < 4; ++j)
        acc[i][j] = mfma_bf16(af[i], bfr[j], acc[i][j]);
    cur ^= 1;
  }

  #pragma unroll
  for (int j = 0; j < 4; ++j) {
    int col = ct * 128 + nq + j * 16 + l16;
    float bb = bf2f(bfc[col]);
    #pragma unroll
    for (int i = 0; i < 4; ++i) {
      #pragma unroll
      for (int r = 0; r < 4; ++r) {
        int m = rt * 128 + mq + i * 16 + quad * 4 + r;
        float val = acc[i][j][r] + bb;
        size_t idx = (size_t)m * HID_ + col;
        if (isf) ((float*)outv)[idx] = val;
        else     ((u16*)outv)[idx]   = f2bf(val);
      }
    }
  }
}

extern "C" void kernel_launch(void* const* d_in, const int* in_sizes, int n_in,
                              void* d_out, int out_size, void* d_ws, size_t ws_size,
                              hipStream_t stream) {
  int* flag = (int*)d_ws;
  u16* conv = (u16*)((char*)d_ws + 16);
  u16* wt   = conv + CONV_TOT;                 // 3*16*64*1024 = 3,145,728
  u16* qw   = wt + 3145728;
  u16* kw   = qw + 4194304;
  u16* vw   = kw + 4194304;
  u16* xw   = vw + 4194304;
  // bf16 copies of Q/K/V inputs. qc overlays xw: proj reads qc; attn writes
  // xw only after proj completes (stream-ordered). kc/vc extend the ws.
  u16* qc   = xw;
  u16* kc   = xw + 4194304;
  u16* vc   = kc + 4194304;

  detect_kernel<<<1, 256, 0, stream>>>((const u16*)d_in[0], flag);

  SrcPtrs sp;
  sp.p[0] = d_in[4];  sp.p[1] = d_in[6];  sp.p[2] = d_in[8];
  sp.p[3] = d_in[9];  sp.p[4] = d_in[10]; sp.p[5] = d_in[11]; sp.p[6] = d_in[12];
  convert_kernel<<<1034, 256, 0, stream>>>(sp, flag, conv);
  qkvconv_kernel<<<2048, 256, 0, stream>>>(d_in[0], d_in[1], d_in[2], flag, qc, kc, vc);

  wtrans_kernel<<<dim3(16, 16, 3), 256, 0, stream>>>(d_in[3], d_in[5], d_in[7], flag, wt);
  proj_kernel<<<dim3(32, 8, 3), 256, 0, stream>>>(qc, kc, vc, wt, conv, qw, kw, vw);
  attn_kernel<<<dim3(16, 16, 4), 256, 0, stream>>>(qw, kw, vw, conv, xw);
  fc_kernel<<<dim3(32, 8), 256, 0, stream>>>(xw, conv, flag, (u16*)d_out);
}

// Round 10
// 295.796 us; speedup vs baseline: 1.1373x; 1.1373x over previous
//
#include <hip/hip_runtime.h>
#include <stdint.h>

#define B_ 4
#define S_ 1024
#define HID_ 1024
#define H_ 16
#define DH_ 64
#define NDIST 33
#define SCALE_ 0.125f

typedef unsigned short u16;
typedef __attribute__((ext_vector_type(8))) short short8;
typedef __attribute__((ext_vector_type(4))) float floatx4;

static __device__ __forceinline__ float bf2f(u16 u) {
  union { unsigned int i; float f; } v; v.i = ((unsigned int)u) << 16; return v.f;
}
static __device__ __forceinline__ u16 f2bf(float x) {
  union { float f; unsigned int i; } v; v.f = x;
  return (u16)((v.i + 0x7FFFu + ((v.i >> 16) & 1u)) >> 16);
}
static __device__ __forceinline__ floatx4 mfma_bf16(short8 a, short8 b, floatx4 c) {
  return __builtin_amdgcn_mfma_f32_16x16x32_bf16(a, b, c, 0, 0, 0);
}
// async global->LDS, 16B per lane. LDS dest = wave-uniform base + lane*16;
// global src is per-lane (m97/m104 verified pattern).
static __device__ __forceinline__ void gload_lds16(const void* g, void* l) {
  __builtin_amdgcn_global_load_lds(
      (const __attribute__((address_space(1))) unsigned int*)g,
      (__attribute__((address_space(3))) unsigned int*)l, 16, 0, 0);
}

// conv region element offsets (u16 units)
#define OFF_BQ   0
#define OFF_BK   1024
#define OFF_BV   2048
#define OFF_RELK 3072
#define OFF_RELV 5184
#define OFF_FCW  7296
#define OFF_FCB  1055872
#define CONV_TOT 1056896

struct SrcPtrs { const void* p[7]; };

// ---------------------------------------------------------------------------
// Dtype detector: fp32 read as u16 pairs -> even halves are mantissa bits ->
// huge as bf16. flag=1 means fp32 inputs.
// ---------------------------------------------------------------------------
__global__ __launch_bounds__(256) void detect_kernel(const u16* __restrict__ q,
                                                     int* __restrict__ flag) {
  __shared__ float red[256];
  float m = 0.f;
  for (int i = threadIdx.x; i < 8192; i += 256) {
    float v = fabsf(bf2f(q[2 * i]));
    m = fmaxf(m, (v < 1e30f) ? v : 1e20f);
  }
  red[threadIdx.x] = m;
  __syncthreads();
  for (int s = 128; s > 0; s >>= 1) {
    if (threadIdx.x < (unsigned)s) red[threadIdx.x] = fmaxf(red[threadIdx.x], red[threadIdx.x + s]);
    __syncthreads();
  }
  if (threadIdx.x == 0) *flag = (red[0] > 1e4f) ? 1 : 0;
}

// ---------------------------------------------------------------------------
// Convert biases / rel tables / fcW to bf16 (copy if already bf16).
// ---------------------------------------------------------------------------
__global__ __launch_bounds__(256) void convert_kernel(SrcPtrs srcs,
                                                      const int* __restrict__ flag,
                                                      u16* __restrict__ dst) {
  constexpr int segsz[7] = {1024,1024,1024,2112,2112,1048576,1024};
  constexpr int cumE[7]  = {OFF_BQ,OFF_BK,OFF_BV,OFF_RELK,OFF_RELV,OFF_FCW,OFF_FCB};
  constexpr int cumB[8]  = {0,1,2,3,6,9,1033,1034};
  const int bid = blockIdx.x;
  int t = 0;
  #pragma unroll
  for (int i = 1; i < 7; ++i) if (bid >= cumB[i]) t = i;
  const int chunk = (bid - cumB[t]) * 1024 + threadIdx.x * 4;
  if (chunk >= segsz[t]) return;
  __align__(8) u16 o[4];
  if (*flag) {
    const float* s = (const float*)srcs.p[t];
    float4 v = *(const float4*)(s + chunk);
    o[0] = f2bf(v.x); o[1] = f2bf(v.y); o[2] = f2bf(v.z); o[3] = f2bf(v.w);
  } else {
    const u16* s = (const u16*)srcs.p[t];
    *(uint2*)o = *(const uint2*)(s + chunk);
  }
  *(uint2*)(dst + cumE[t] + chunk) = *(const uint2*)o;
}

// ---------------------------------------------------------------------------
// Q/K/V input -> bf16 (copy if already bf16). 3 x [4096][1024], 8 elems/thr,
// grid-stride. Same f2bf as the old in-proj convert -> bit-identical values.
// ---------------------------------------------------------------------------
__global__ __launch_bounds__(256) void qkvconv_kernel(
    const void* __restrict__ qin, const void* __restrict__ kin,
    const void* __restrict__ vin, const int* __restrict__ flag,
    u16* __restrict__ qc, u16* __restrict__ kc, u16* __restrict__ vc)
{
  const int isf = *flag;
  const int total = 3 * (4096 * 1024 / 8);          // 1,572,864 groups
  for (int g = blockIdx.x * 256 + threadIdx.x; g < total; g += gridDim.x * 256) {
    const int z = g >> 19;                          // 524288 groups per tensor
    const int off = (g & 524287) * 8;
    const void* src = (z == 0) ? qin : (z == 1) ? kin : vin;
    u16* dst = (z == 0) ? qc : (z == 1) ? kc : vc;
    if (isf) {
      const float* s = (const float*)src + off;
      float4 v0 = *(const float4*)s;
      float4 v1 = *(const float4*)(s + 4);
      __align__(16) u16 tmp[8] = {f2bf(v0.x),f2bf(v0.y),f2bf(v0.z),f2bf(v0.w),
                                  f2bf(v1.x),f2bf(v1.y),f2bf(v1.z),f2bf(v1.w)};
      *(uint4*)(dst + off) = *(const uint4*)tmp;
    } else {
      *(uint4*)(dst + off) = *(const uint4*)((const u16*)src + off);
    }
  }
}

// ---------------------------------------------------------------------------
// W transpose: raw W [h][d][e] (fp32 or bf16) -> wt[z][h*64+e][d] bf16.
// grid (16 d-tiles, 16 h, 3 z), block 256.
// ---------------------------------------------------------------------------
__global__ __launch_bounds__(256) void wtrans_kernel(
    const void* __restrict__ Wq, const void* __restrict__ Wk, const void* __restrict__ Wv,
    const int* __restrict__ flag, u16* __restrict__ wt)
{
  const int dt = blockIdx.x, h = blockIdx.y, z = blockIdx.z;
  const void* W = (z == 0) ? Wq : (z == 1) ? Wk : Wv;
  const int tid = threadIdx.x;
  const int isf = *flag;
  __shared__ __align__(16) u16 t_l[64 * 72];

  #pragma unroll
  for (int i = 0; i < 2; ++i) {
    int g = tid + 256 * i;
    int d = g & 63, e8 = (g >> 6) * 8;
    size_t off = ((size_t)h * HID_ + dt * 64 + d) * DH_ + e8;
    __align__(16) u16 tmp[8];
    if (isf) {
      const float* Wf = (const float*)W + off;
      float4 v0 = *(const float4*)Wf;
      float4 v1 = *(const float4*)(Wf + 4);
      tmp[0]=f2bf(v0.x); tmp[1]=f2bf(v0.y); tmp[2]=f2bf(v0.z); tmp[3]=f2bf(v0.w);
      tmp[4]=f2bf(v1.x); tmp[5]=f2bf(v1.y); tmp[6]=f2bf(v1.z); tmp[7]=f2bf(v1.w);
    } else {
      *(uint4*)tmp = *(const uint4*)((const u16*)W + off);
    }
    #pragma unroll
    for (int j = 0; j < 8; ++j) {
      int e = e8 + j;
      t_l[e * 72 + (((d >> 3) ^ (e & 7)) << 3) + (d & 7)] = tmp[j];
    }
  }
  __syncthreads();
  {
    int e = tid >> 2, c0 = (tid & 3) * 2;
    u16* dst = wt + ((size_t)(z * H_ + h) * DH_ + e) * HID_ + dt * 64;
    uint4 x0 = *(const uint4*)(t_l + e * 72 + (((c0    ) ^ (e & 7)) << 3));
    uint4 x1 = *(const uint4*)(t_l + e * 72 + (((c0 + 1) ^ (e & 7)) << 3));
    *(uint4*)(dst + c0 * 8)     = x0;
    *(uint4*)(dst + c0 * 8 + 8) = x1;
  }
}

// ---------------------------------------------------------------------------
// Q/K/V projection GEMM: [4096 x 1024] @ Wcat^T, 128x128 tile, BK=32.
// Double-buffered LDS, one barrier per K-step, pure global_load_lds staging,
// chunk-XOR swizzle (verified round 7). This revision adds a bijective
// XCD-aware block swizzle: XCD x owns panels p in {3x,3x+1,3x+2} (p=z*8+ct)
// x all 32 rt. Per-XCD B residency = 3 panels x 256KB = 768KB (L2-fits for
// the kernel lifetime; default round-robin needed all 24 panels = 6MB ->
// thrash). Blocks sharing an A-tile are co-located & concurrent -> A k-slice
// L2 hits. grid (32, 8, 3), block 256.
// ---------------------------------------------------------------------------
__global__ __launch_bounds__(256, 3) void proj_kernel(
    const u16* __restrict__ qc, const u16* __restrict__ kc, const u16* __restrict__ vc,
    const u16* __restrict__ wt, const u16* __restrict__ conv,
    u16* __restrict__ qo, u16* __restrict__ ko, u16* __restrict__ vo)
{
  // XCD-bijective remap: bid -> (rt, ct, z)
  const int bid = blockIdx.x + 32 * (blockIdx.y + 8 * blockIdx.z);  // [0,768)
  const int xcd = bid & 7, local = bid >> 3;        // local in [0,96)
  const int p  = xcd * 3 + (local >> 5);            // panel in [0,24)
  const int rt = local & 31;
  const int z  = p >> 3, ct = p & 7;

  const u16* A    = (z == 0) ? qc : (z == 1) ? kc : vc;
  const u16* Wz   = wt + (size_t)z * (H_ * DH_ * HID_);
  const u16* bias = conv + ((z == 0) ? OFF_BQ : (z == 1) ? OFF_BK : OFF_BV);
  u16*       O    = (z == 0) ? qo : (z == 1) ? ko : vo;
  const int tid = threadIdx.x, lane = tid & 63, w = tid >> 6, quad = lane >> 4, l16 = lane & 15;

  __shared__ __align__(16) u16 a_l[2][128 * 32];
  __shared__ __align__(16) u16 b_l[2][128 * 32];

  floatx4 acc[4][4];
  #pragma unroll
  for (int i = 0; i < 4; ++i)
    #pragma unroll
    for (int j = 0; j < 4; ++j) acc[i][j] = (floatx4){0.f,0.f,0.f,0.f};

  const int mq = (w & 1) * 64, nq = (w >> 1) * 64;
  const int u = (lane & 3) ^ ((lane >> 3) & 3);   // inverse-swizzled src chunk
  const int cs = (quad ^ ((l16 >> 1) & 3)) * 8;   // swizzled read chunk offset

  auto STAGE = [&](int bu, int kk) {
    #pragma unroll
    for (int i = 0; i < 2; ++i) {
      int row = (tid + 256 * i) >> 2;
      gload_lds16(A  + (size_t)(rt * 128 + row) * HID_ + kk * 32 + u * 8,
                  a_l[bu] + (w * 64 + i * 256) * 8);
      gload_lds16(Wz + (size_t)(ct * 128 + row) * HID_ + kk * 32 + u * 8,
                  b_l[bu] + (w * 64 + i * 256) * 8);
    }
  };

  STAGE(0, 0);
  int cur = 0;
  for (int kk = 0; kk < 32; ++kk) {
    __syncthreads();            // drains vmcnt -> buf[cur] complete; orders prev reads
    if (kk + 1 < 32) STAGE(cur ^ 1, kk + 1);
    const u16* ab = a_l[cur];
    const u16* bb = b_l[cur];
    short8 af[4], bfr[4];
    #pragma unroll
    for (int i = 0; i < 4; ++i) {
      af[i]  = *(const short8*)(ab + (mq + i * 16 + l16) * 32 + cs);
      bfr[i] = *(const short8*)(bb + (nq + i * 16 + l16) * 32 + cs);
    }
    #pragma unroll
    for (int i = 0; i < 4; ++i)
      #pragma unroll
      for (int j = 0; j < 4; ++j)
        acc[i][j] = mfma_bf16(af[i], bfr[j], acc[i][j]);
    cur ^= 1;
  }

  #pragma unroll
  for (int j = 0; j < 4; ++j) {
    int col = ct * 128 + nq + j * 16 + l16;
    int hh = col >> 6, e = col & 63;
    float bb = bf2f(bias[hh * 64 + e]);
    #pragma unroll
    for (int i = 0; i < 4; ++i) {
      #pragma unroll
      for (int r = 0; r < 4; ++r) {
        int m = rt * 128 + mq + i * 16 + quad * 4 + r;
        int bidx = m >> 10, srow = m & 1023;
        O[(((size_t)(bidx * H_ + hh)) * S_ + srow) * DH_ + e] = f2bf(acc[i][j][r] + bb);
      }
    }
  }
}

// ---------------------------------------------------------------------------
// Fused attention, q-tile 64 x k-tile 64, 16 k-steps, 2 barriers each.
// REVERTED to verified round-8 kernel (89.2 us). Round-9's direct per-element
// atomicAdd regressed +54%: for dkt=+-1 tiles ~75% of elements clamp to
// dist 0/32 -> same-address ds_add serializes per lane (not counted as bank
// conflict). The shfl butterfly pre-aggregation of the clamped tails is
// load-bearing; keep it.
// grid (16, 16, 4), block 256.
// ---------------------------------------------------------------------------
__global__ __launch_bounds__(256, 4) void attn_kernel(
    const u16* __restrict__ Q, const u16* __restrict__ K, const u16* __restrict__ V,
    const u16* __restrict__ conv, u16* __restrict__ Ox)
{
  // XCD-aware bijective swizzle of the flat block id (1024 blocks, 8 XCDs)
  const int bid = blockIdx.x + 16 * (blockIdx.y + 16 * blockIdx.z);
  const int nid = (bid & 7) * 128 + (bid >> 3);
  const int qt = nid & 15, h = (nid >> 4) & 15, b = nid >> 8;

  const int tid = threadIdx.x;
  const int lane = tid & 63, w = tid >> 6, quad = lane >> 4, l16 = lane & 15;
  const size_t base = ((size_t)(b * H_ + h)) * S_ * DH_;
  const u16* Kb = K + base;
  const u16* Vb = V + base;

  __shared__ __align__(16) char smem[40320];
  u16*   p_l    = (u16*)(smem);            // [64][72]; preamble: Q tile; epilogue: Bfull
  u16*   q_l    = p_l;                     // alias (dead after preamble)
  u16*   k_l    = (u16*)(smem + 9216);     // [64][72]; epilogue: relv^T [64 e][72]
  u16*   vt_l   = (u16*)(smem + 18432);    // [64 e][72] plain V^T (row e, col k)
  u16*   rq_l   = (u16*)(smem + 27648);    // [64][33] bf16 (near tiles only)
  float* bucket = (float*)(smem + 31872);  // [64][33]; preamble: relk_b u16 [48][72]
  u16*   rkb    = (u16*)(smem + 31872);

  // issue kt=0 K/V loads immediately; the whole preamble covers their latency
  uint4 kr0 = *(const uint4*)(Kb + (size_t)(tid >> 3) * DH_ + (tid & 7) * 8);
  uint4 kr1 = *(const uint4*)(Kb + (size_t)((tid >> 3) + 32) * DH_ + (tid & 7) * 8);
  uint4 vr0 = *(const uint4*)(Vb + (size_t)lane * DH_ + w * 16);
  uint4 vr1 = *(const uint4*)(Vb + (size_t)lane * DH_ + w * 16 + 8);

  // preamble: stage Q tile + relk (B-layout rows, zero-padded to 48)
  #pragma unroll
  for (int i = 0; i < 2; ++i) {
    int idx = tid + 256 * i;
    int row = idx >> 3, c8 = (idx & 7) * 8;
    *(uint4*)(q_l + row * 72 + c8) =
        *(const uint4*)(Q + base + (size_t)(qt * 64 + row) * DH_ + c8);
  }
  const u16* relk = conv + OFF_RELK;
  for (int idx = tid; idx < 48 * 8; idx += 256) {
    int row = idx >> 3, c8 = (idx & 7) * 8;
    uint4 v = make_uint4(0, 0, 0, 0);
    if (row < NDIST) v = *(const uint4*)(relk + row * 64 + c8);
    *(uint4*)(rkb + row * 72 + c8) = v;
  }
  __syncthreads();

  const int m0 = w * 16;
  short8 qa0 = *(const short8*)(q_l + (m0 + l16) * 72 + quad * 8);
  short8 qa1 = *(const short8*)(q_l + (m0 + l16) * 72 + 32 + quad * 8);

  // RQ[m][d] = q[m,:] . relk[d,:]  (capture d=0 / d=32 accumulators)
  floatx4 c_d0 = {0.f,0.f,0.f,0.f}, c_d32 = {0.f,0.f,0.f,0.f};
  #pragma unroll
  for (int t3 = 0; t3 < 3; ++t3) {
    floatx4 c = {0.f,0.f,0.f,0.f};
    c = mfma_bf16(qa0, *(const short8*)(rkb + (t3 * 16 + l16) * 72 + quad * 8), c);
    c = mfma_bf16(qa1, *(const short8*)(rkb + (t3 * 16 + l16) * 72 + 32 + quad * 8), c);
    if (t3 == 0) c_d0 = c;
    if (t3 == 2) c_d32 = c;
    int d = t3 * 16 + l16;
    if (d < NDIST) {
      #pragma unroll
      for (int r = 0; r < 4; ++r) rq_l[(m0 + quad * 4 + r) * 33 + d] = f2bf(c[r]);
    }
  }
  // far-tile bias: RQ[m][0]/RQ[m][32] held by lane quad*16+0 (col=lane&15=0);
  // broadcast, apply the same bf16 round-trip, pre-scale.
  float rqs_lo[4], rqs_hi[4];
  #pragma unroll
  for (int r = 0; r < 4; ++r) {
    rqs_lo[r] = bf2f(f2bf(__shfl(c_d0[r],  lane & 48, 64))) * SCALE_;
    rqs_hi[r] = bf2f(f2bf(__shfl(c_d32[r], lane & 48, 64))) * SCALE_;
  }
  __syncthreads();              // relk_b/q_l reads done -> regions become bucket/p_l
  for (int idx = tid; idx < 64 * 33; idx += 256) bucket[idx] = 0.f;

  floatx4 o[4], oi = {0.f,0.f,0.f,0.f};
  #pragma unroll
  for (int t = 0; t < 4; ++t) o[t] = (floatx4){0.f,0.f,0.f,0.f};

  for (int kt = 0; kt < 16; ++kt) {
    __syncthreads();            // prev iter LDS reads done (kt=0: bucket zero visible)
    // write-late: staged registers -> LDS (vmcnt wait forced by reg dataflow)
    *(uint4*)(k_l + (tid >> 3) * 72 + (tid & 7) * 8) = kr0;
    *(uint4*)(k_l + ((tid >> 3) + 32) * 72 + (tid & 7) * 8) = kr1;
    {
      const u16* t8 = (const u16*)&vr0;
      #pragma unroll
      for (int j = 0; j < 8; ++j) vt_l[(w * 16 + j) * 72 + lane] = t8[j];
      const u16* t9 = (const u16*)&vr1;
      #pragma unroll
      for (int j = 0; j < 8; ++j) vt_l[(w * 16 + 8 + j) * 72 + lane] = t9[j];
    }
    __syncthreads();
    // issue-early: next tile's loads fly under the whole compute phase
    if (kt < 15) {
      const size_t kb = (size_t)((kt + 1) * 64);
      kr0 = *(const uint4*)(Kb + (kb + (tid >> 3)) * DH_ + (tid & 7) * 8);
      kr1 = *(const uint4*)(Kb + (kb + (tid >> 3) + 32) * DH_ + (tid & 7) * 8);
      vr0 = *(const uint4*)(Vb + (kb + lane) * DH_ + w * 16);
      vr1 = *(const uint4*)(Vb + (kb + lane) * DH_ + w * 16 + 8);
    }

    const int dkt = kt - qt;
    const bool near = (dkt >= -1) && (dkt <= 1);

    #pragma unroll
    for (int t = 0; t < 4; ++t) {
      floatx4 s = {0.f,0.f,0.f,0.f};
      s = mfma_bf16(qa0, *(const short8*)(k_l + (t * 16 + l16) * 72 + quad * 8), s);
      s = mfma_bf16(qa1, *(const short8*)(k_l + (t * 16 + l16) * 72 + 32 + quad * 8), s);
      int kcol = t * 16 + l16;
      if (near) {
        #pragma unroll
        for (int r = 0; r < 4; ++r) {
          int m = m0 + quad * 4 + r;
          int delta = (kt * 64 + kcol) - (qt * 64 + m);
          int dist = (delta < -16 ? -16 : (delta > 16 ? 16 : delta)) + 16;
          float logit = (s[r] + bf2f(rq_l[m * 33 + dist])) * SCALE_;
          u16 pu = f2bf(__expf(fminf(logit, 30.f)));
          p_l[m * 72 + kcol] = pu;
          float pv = bf2f(pu);
          float vhi = (dist == 32) ? pv : 0.f;
          float vlo = (dist == 0) ? pv : 0.f;
          #pragma unroll
          for (int off2 = 1; off2 < 16; off2 <<= 1) {
            vhi += __shfl_xor(vhi, off2, 16);
            vlo += __shfl_xor(vlo, off2, 16);
          }
          if (l16 == 0) {
            if (vhi != 0.f) atomicAdd(&bucket[m * 33 + 32], vhi);
            if (vlo != 0.f) atomicAdd(&bucket[m * 33 + 0], vlo);
          }
          if (dist > 0 && dist < 32) atomicAdd(&bucket[m * 33 + dist], pv);
        }
      } else {
        #pragma unroll
        for (int r = 0; r < 4; ++r) {
          int m = m0 + quad * 4 + r;
          float logit = fmaf(s[r], SCALE_, (dkt < 0) ? rqs_lo[r] : rqs_hi[r]);
          u16 pu = f2bf(__expf(fminf(logit, 30.f)));
          p_l[m * 72 + kcol] = pu;
        }
      }
    }

    // PV + far-tile indicator row-sums (same-wave P round-trip, no barrier)
    u16 iv = ((l16 == 0 && dkt <= -2) || (l16 == 1 && dkt >= 2)) ? (u16)0x3F80 : (u16)0;
    short8 ib;
    #pragma unroll
    for (int j = 0; j < 8; ++j) ib[j] = (short)iv;
    short8 pa0 = *(const short8*)(p_l + (m0 + l16) * 72 + quad * 8);
    short8 pa1 = *(const short8*)(p_l + (m0 + l16) * 72 + 32 + quad * 8);
    oi = mfma_bf16(pa0, ib, oi);
    oi = mfma_bf16(pa1, ib, oi);
    #pragma unroll
    for (int t = 0; t < 4; ++t) {
      int e = t * 16 + l16;
      short8 vb0 = *(const short8*)(vt_l + e * 72 + quad * 8);
      short8 vb1 = *(const short8*)(vt_l + e * 72 + 32 + quad * 8);
      o[t] = mfma_bf16(pa0, vb0, o[t]);
      o[t] = mfma_bf16(pa1, vb1, o[t]);
    }
  }

  __syncthreads();              // loop LDS use + atomics done
  // fold far sums (s_lo at col0, s_hi at col1 of oi) into bucket
  if (l16 == 0) {
    #pragma unroll
    for (int r = 0; r < 4; ++r) bucket[(m0 + quad * 4 + r) * 33 + 0] += oi[r];
  } else if (l16 == 1) {
    #pragma unroll
    for (int r = 0; r < 4; ++r) bucket[(m0 + quad * 4 + r) * 33 + 32] += oi[r];
  }
  __syncthreads();

  u16* rvT = k_l;               // relv^T [64 e][72]
  u16* Bf  = p_l;               // Bfull bf16 [64 m][72]
  for (int idx = tid; idx < 576; idx += 256) {
    ((uint4*)rvT)[idx] = make_uint4(0, 0, 0, 0);
    ((uint4*)Bf)[idx]  = make_uint4(0, 0, 0, 0);
  }
  __syncthreads();
  const u16* relv = conv + OFF_RELV;
  for (int idx = tid; idx < NDIST * 64; idx += 256) {
    int d = idx >> 6, e = idx & 63;
    rvT[e * 72 + d] = relv[idx];
  }
  for (int idx = tid; idx < 64 * NDIST; idx += 256) {
    int m = idx / NDIST, d = idx - m * NDIST;
    Bf[m * 72 + d] = f2bf(bucket[m * 33 + d]);
  }
  __syncthreads();

  // o += Bfull @ relv
  short8 ba0 = *(const short8*)(Bf + (m0 + l16) * 72 + quad * 8);
  short8 ba1 = *(const short8*)(Bf + (m0 + l16) * 72 + 32 + quad * 8);
  #pragma unroll
  for (int t = 0; t < 4; ++t) {
    short8 rb0 = *(const short8*)(rvT + (t * 16 + l16) * 72 + quad * 8);
    short8 rb1 = *(const short8*)(rvT + (t * 16 + l16) * 72 + 32 + quad * 8);
    o[t] = mfma_bf16(ba0, rb0, o[t]);
    o[t] = mfma_bf16(ba1, rb1, o[t]);
  }

  float rl[4];
  #pragma unroll
  for (int r = 0; r < 4; ++r) {
    int m = m0 + quad * 4 + r;
    float s = 0.f;
    #pragma unroll
    for (int d = 0; d < NDIST; ++d) s += bucket[m * 33 + d];
    rl[r] = 1.f / s;
  }

  #pragma unroll
  for (int t = 0; t < 4; ++t) {
    int e = t * 16 + l16;
    #pragma unroll
    for (int r = 0; r < 4; ++r) {
      int srow = qt * 64 + m0 + quad * 4 + r;
      Ox[((size_t)(b * S_ + srow)) * HID_ + h * 64 + e] = f2bf(o[t][r] * rl[r]);
    }
  }
}

// ---------------------------------------------------------------------------
// fc: out = X @ fcW^T + b. X bf16 [4096][1024] (ws), fcW k-contiguous.
// Same dbuf + 1-barrier + chunk-XOR-swizzle structure as proj, plus XCD
// swizzle: XCD x owns ct=x for all rt -> B panel 256KB L2-resident.
// 128x128 tile, BK=32, grid (32, 8), block 256. Dual-dtype output.
// ---------------------------------------------------------------------------
__global__ __launch_bounds__(256, 3) void fc_kernel(
    const u16* __restrict__ X, const u16* __restrict__ conv,
    const int* __restrict__ flag, void* __restrict__ outv)
{
  const u16* Wf  = conv + OFF_FCW;
  const u16* bfc = conv + OFF_FCB;
  // XCD-bijective remap: XCD x <- ct = x, rt = bid/8
  const int bid = blockIdx.x + 32 * blockIdx.y;     // [0,256)
  const int ct = bid & 7, rt = bid >> 3;
  const int tid = threadIdx.x, lane = tid & 63, w = tid >> 6, quad = lane >> 4, l16 = lane & 15;
  const int isf = *flag;

  __shared__ __align__(16) u16 a_l[2][128 * 32];
  __shared__ __align__(16) u16 b_l[2][128 * 32];

  floatx4 acc[4][4];
  #pragma unroll
  for (int i = 0; i < 4; ++i)
    #pragma unroll
    for (int j = 0; j < 4; ++j) acc[i][j] = (floatx4){0.f,0.f,0.f,0.f};

  const int mq = (w & 1) * 64, nq = (w >> 1) * 64;
  const int u = (lane & 3) ^ ((lane >> 3) & 3);
  const int cs = (quad ^ ((l16 >> 1) & 3)) * 8;

  auto STAGE = [&](int bu, int kk) {
    #pragma unroll
    for (int i = 0; i < 2; ++i) {
      int row = (tid + 256 * i) >> 2;
      gload_lds16(X  + (size_t)(rt * 128 + row) * HID_ + kk * 32 + u * 8,
                  a_l[bu] + (w * 64 + i * 256) * 8);
      gload_lds16(Wf + (size_t)(ct * 128 + row) * HID_ + kk * 32 + u * 8,
                  b_l[bu] + (w * 64 + i * 256) * 8);
    }
  };

  STAGE(0, 0);
  int cur = 0;
  for (int kk = 0; kk < 32; ++kk) {
    __syncthreads();
    if (kk + 1 < 32) STAGE(cur ^ 1, kk + 1);
    const u16* ab = a_l[cur];
    const u16* bb = b_l[cur];
    short8 af[4], bfr[4];
    #pragma unroll
    for (int i = 0; i < 4; ++i) {
      af[i]  = *(const short8*)(ab + (mq + i * 16 + l16) * 32 + cs);
      bfr[i] = *(const short8*)(bb + (nq + i * 16 + l16) * 32 + cs);
    }
    #pragma unroll
    for (int i = 0; i < 4; ++i)
      #pragma unroll
      for (int j = 0; j < 4; ++j)
        acc[i][j] = mfma_bf16(af[i], bfr[j], acc[i][j]);
    cur ^= 1;
  }

  #pragma unroll
  for (int j = 0; j < 4; ++j) {
    int col = ct * 128 + nq + j * 16 + l16;
    float bb = bf2f(bfc[col]);
    #pragma unroll
    for (int i = 0; i < 4; ++i) {
      #pragma unroll
      for (int r = 0; r < 4; ++r) {
        int m = rt * 128 + mq + i * 16 + quad * 4 + r;
        float val = acc[i][j][r] + bb;
        size_t idx = (size_t)m * HID_ + col;
        if (isf) ((float*)outv)[idx] = val;
        else     ((u16*)outv)[idx]   = f2bf(val);
      }
    }
  }
}

extern "C" void kernel_launch(void* const* d_in, const int* in_sizes, int n_in,
                              void* d_out, int out_size, void* d_ws, size_t ws_size,
                              hipStream_t stream) {
  int* flag = (int*)d_ws;
  u16* conv = (u16*)((char*)d_ws + 16);
  u16* wt   = conv + CONV_TOT;                 // 3*16*64*1024 = 3,145,728
  u16* qw   = wt + 3145728;
  u16* kw   = qw + 4194304;
  u16* vw   = kw + 4194304;
  u16* xw   = vw + 4194304;
  // bf16 copies of Q/K/V inputs. qc overlays xw: proj reads qc; attn writes
  // xw only after proj completes (stream-ordered). kc/vc extend the ws.
  u16* qc   = xw;
  u16* kc   = xw + 4194304;
  u16* vc   = kc + 4194304;

  detect_kernel<<<1, 256, 0, stream>>>((const u16*)d_in[0], flag);

  SrcPtrs sp;
  sp.p[0] = d_in[4];  sp.p[1] = d_in[6];  sp.p[2] = d_in[8];
  sp.p[3] = d_in[9];  sp.p[4] = d_in[10]; sp.p[5] = d_in[11]; sp.p[6] = d_in[12];
  convert_kernel<<<1034, 256, 0, stream>>>(sp, flag, conv);
  qkvconv_kernel<<<2048, 256, 0, stream>>>(d_in[0], d_in[1], d_in[2], flag, qc, kc, vc);

  wtrans_kernel<<<dim3(16, 16, 3), 256, 0, stream>>>(d_in[3], d_in[5], d_in[7], flag, wt);
  proj_kernel<<<dim3(32, 8, 3), 256, 0, stream>>>(qc, kc, vc, wt, conv, qw, kw, vw);
  attn_kernel<<<dim3(16, 16, 4), 256, 0, stream>>>(qw, kw, vw, conv, xw);
  fc_kernel<<<dim3(32, 8), 256, 0, stream>>>(xw, conv, flag, (u16*)d_out);
}

// Round 11
// 265.980 us; speedup vs baseline: 1.2648x; 1.1121x over previous
//
#include <hip/hip_runtime.h>
#include <stdint.h>

#define B_ 4
#define S_ 1024
#define HID_ 1024
#define H_ 16
#define DH_ 64
#define NDIST 33
#define SCALE_ 0.125f

typedef unsigned short u16;
typedef __attribute__((ext_vector_type(8))) short short8;
typedef __attribute__((ext_vector_type(4))) float floatx4;

static __device__ __forceinline__ float bf2f(u16 u) {
  union { unsigned int i; float f; } v; v.i = ((unsigned int)u) << 16; return v.f;
}
static __device__ __forceinline__ u16 f2bf(float x) {
  union { float f; unsigned int i; } v; v.f = x;
  return (u16)((v.i + 0x7FFFu + ((v.i >> 16) & 1u)) >> 16);
}
static __device__ __forceinline__ floatx4 mfma_bf16(short8 a, short8 b, floatx4 c) {
  return __builtin_amdgcn_mfma_f32_16x16x32_bf16(a, b, c, 0, 0, 0);
}
// async global->LDS, 16B per lane. LDS dest = wave-uniform base + lane*16;
// global src is per-lane (m97/m104 verified pattern).
static __device__ __forceinline__ void gload_lds16(const void* g, void* l) {
  __builtin_amdgcn_global_load_lds(
      (const __attribute__((address_space(1))) unsigned int*)g,
      (__attribute__((address_space(3))) unsigned int*)l, 16, 0, 0);
}

// conv region element offsets (u16 units)
#define OFF_BQ   0
#define OFF_BK   1024
#define OFF_BV   2048
#define OFF_RELK 3072
#define OFF_RELV 5184
#define OFF_FCW  7296
#define OFF_FCB  1055872
#define CONV_TOT 1056896

struct SrcPtrs { const void* p[7]; };

// ---------------------------------------------------------------------------
// Dtype detector: fp32 read as u16 pairs -> even halves are mantissa bits ->
// huge as bf16. flag=1 means fp32 inputs.
// ---------------------------------------------------------------------------
__global__ __launch_bounds__(256) void detect_kernel(const u16* __restrict__ q,
                                                     int* __restrict__ flag) {
  __shared__ float red[256];
  float m = 0.f;
  for (int i = threadIdx.x; i < 8192; i += 256) {
    float v = fabsf(bf2f(q[2 * i]));
    m = fmaxf(m, (v < 1e30f) ? v : 1e20f);
  }
  red[threadIdx.x] = m;
  __syncthreads();
  for (int s = 128; s > 0; s >>= 1) {
    if (threadIdx.x < (unsigned)s) red[threadIdx.x] = fmaxf(red[threadIdx.x], red[threadIdx.x + s]);
    __syncthreads();
  }
  if (threadIdx.x == 0) *flag = (red[0] > 1e4f) ? 1 : 0;
}

// ---------------------------------------------------------------------------
// Convert biases / rel tables / fcW to bf16 (copy if already bf16).
// ---------------------------------------------------------------------------
__global__ __launch_bounds__(256) void convert_kernel(SrcPtrs srcs,
                                                      const int* __restrict__ flag,
                                                      u16* __restrict__ dst) {
  constexpr int segsz[7] = {1024,1024,1024,2112,2112,1048576,1024};
  constexpr int cumE[7]  = {OFF_BQ,OFF_BK,OFF_BV,OFF_RELK,OFF_RELV,OFF_FCW,OFF_FCB};
  constexpr int cumB[8]  = {0,1,2,3,6,9,1033,1034};
  const int bid = blockIdx.x;
  int t = 0;
  #pragma unroll
  for (int i = 1; i < 7; ++i) if (bid >= cumB[i]) t = i;
  const int chunk = (bid - cumB[t]) * 1024 + threadIdx.x * 4;
  if (chunk >= segsz[t]) return;
  __align__(8) u16 o[4];
  if (*flag) {
    const float* s = (const float*)srcs.p[t];
    float4 v = *(const float4*)(s + chunk);
    o[0] = f2bf(v.x); o[1] = f2bf(v.y); o[2] = f2bf(v.z); o[3] = f2bf(v.w);
  } else {
    const u16* s = (const u16*)srcs.p[t];
    *(uint2*)o = *(const uint2*)(s + chunk);
  }
  *(uint2*)(dst + cumE[t] + chunk) = *(const uint2*)o;
}

// ---------------------------------------------------------------------------
// Q/K/V input -> bf16 (copy if already bf16). 3 x [4096][1024], 8 elems/thr,
// grid-stride. Same f2bf as the old in-proj convert -> bit-identical values.
// ---------------------------------------------------------------------------
__global__ __launch_bounds__(256) void qkvconv_kernel(
    const void* __restrict__ qin, const void* __restrict__ kin,
    const void* __restrict__ vin, const int* __restrict__ flag,
    u16* __restrict__ qc, u16* __restrict__ kc, u16* __restrict__ vc)
{
  const int isf = *flag;
  const int total = 3 * (4096 * 1024 / 8);          // 1,572,864 groups
  for (int g = blockIdx.x * 256 + threadIdx.x; g < total; g += gridDim.x * 256) {
    const int z = g >> 19;                          // 524288 groups per tensor
    const int off = (g & 524287) * 8;
    const void* src = (z == 0) ? qin : (z == 1) ? kin : vin;
    u16* dst = (z == 0) ? qc : (z == 1) ? kc : vc;
    if (isf) {
      const float* s = (const float*)src + off;
      float4 v0 = *(const float4*)s;
      float4 v1 = *(const float4*)(s + 4);
      __align__(16) u16 tmp[8] = {f2bf(v0.x),f2bf(v0.y),f2bf(v0.z),f2bf(v0.w),
                                  f2bf(v1.x),f2bf(v1.y),f2bf(v1.z),f2bf(v1.w)};
      *(uint4*)(dst + off) = *(const uint4*)tmp;
    } else {
      *(uint4*)(dst + off) = *(const uint4*)((const u16*)src + off);
    }
  }
}

// ---------------------------------------------------------------------------
// W transpose: raw W [h][d][e] (fp32 or bf16) -> wt[z][h*64+e][d] bf16.
// grid (16 d-tiles, 16 h, 3 z), block 256.
// ---------------------------------------------------------------------------
__global__ __launch_bounds__(256) void wtrans_kernel(
    const void* __restrict__ Wq, const void* __restrict__ Wk, const void* __restrict__ Wv,
    const int* __restrict__ flag, u16* __restrict__ wt)
{
  const int dt = blockIdx.x, h = blockIdx.y, z = blockIdx.z;
  const void* W = (z == 0) ? Wq : (z == 1) ? Wk : Wv;
  const int tid = threadIdx.x;
  const int isf = *flag;
  __shared__ __align__(16) u16 t_l[64 * 72];

  #pragma unroll
  for (int i = 0; i < 2; ++i) {
    int g = tid + 256 * i;
    int d = g & 63, e8 = (g >> 6) * 8;
    size_t off = ((size_t)h * HID_ + dt * 64 + d) * DH_ + e8;
    __align__(16) u16 tmp[8];
    if (isf) {
      const float* Wf = (const float*)W + off;
      float4 v0 = *(const float4*)Wf;
      float4 v1 = *(const float4*)(Wf + 4);
      tmp[0]=f2bf(v0.x); tmp[1]=f2bf(v0.y); tmp[2]=f2bf(v0.z); tmp[3]=f2bf(v0.w);
      tmp[4]=f2bf(v1.x); tmp[5]=f2bf(v1.y); tmp[6]=f2bf(v1.z); tmp[7]=f2bf(v1.w);
    } else {
      *(uint4*)tmp = *(const uint4*)((const u16*)W + off);
    }
    #pragma unroll
    for (int j = 0; j < 8; ++j) {
      int e = e8 + j;
      t_l[e * 72 + (((d >> 3) ^ (e & 7)) << 3) + (d & 7)] = tmp[j];
    }
  }
  __syncthreads();
  {
    int e = tid >> 2, c0 = (tid & 3) * 2;
    u16* dst = wt + ((size_t)(z * H_ + h) * DH_ + e) * HID_ + dt * 64;
    uint4 x0 = *(const uint4*)(t_l + e * 72 + (((c0    ) ^ (e & 7)) << 3));
    uint4 x1 = *(const uint4*)(t_l + e * 72 + (((c0 + 1) ^ (e & 7)) << 3));
    *(uint4*)(dst + c0 * 8)     = x0;
    *(uint4*)(dst + c0 * 8 + 8) = x1;
  }
}

// ---------------------------------------------------------------------------
// Q/K/V projection GEMM: [4096 x 1024] @ Wcat^T, 128x128 tile, BK=32.
// Double-buffered LDS, one barrier per K-step, pure global_load_lds staging,
// chunk-XOR swizzle, XCD-bijective panel swizzle. grid (32, 8, 3), block 256.
// ---------------------------------------------------------------------------
__global__ __launch_bounds__(256, 3) void proj_kernel(
    const u16* __restrict__ qc, const u16* __restrict__ kc, const u16* __restrict__ vc,
    const u16* __restrict__ wt, const u16* __restrict__ conv,
    u16* __restrict__ qo, u16* __restrict__ ko, u16* __restrict__ vo)
{
  // XCD-bijective remap: bid -> (rt, ct, z)
  const int bid = blockIdx.x + 32 * (blockIdx.y + 8 * blockIdx.z);  // [0,768)
  const int xcd = bid & 7, local = bid >> 3;        // local in [0,96)
  const int p  = xcd * 3 + (local >> 5);            // panel in [0,24)
  const int rt = local & 31;
  const int z  = p >> 3, ct = p & 7;

  const u16* A    = (z == 0) ? qc : (z == 1) ? kc : vc;
  const u16* Wz   = wt + (size_t)z * (H_ * DH_ * HID_);
  const u16* bias = conv + ((z == 0) ? OFF_BQ : (z == 1) ? OFF_BK : OFF_BV);
  u16*       O    = (z == 0) ? qo : (z == 1) ? ko : vo;
  const int tid = threadIdx.x, lane = tid & 63, w = tid >> 6, quad = lane >> 4, l16 = lane & 15;

  __shared__ __align__(16) u16 a_l[2][128 * 32];
  __shared__ __align__(16) u16 b_l[2][128 * 32];

  floatx4 acc[4][4];
  #pragma unroll
  for (int i = 0; i < 4; ++i)
    #pragma unroll
    for (int j = 0; j < 4; ++j) acc[i][j] = (floatx4){0.f,0.f,0.f,0.f};

  const int mq = (w & 1) * 64, nq = (w >> 1) * 64;
  const int u = (lane & 3) ^ ((lane >> 3) & 3);   // inverse-swizzled src chunk
  const int cs = (quad ^ ((l16 >> 1) & 3)) * 8;   // swizzled read chunk offset

  auto STAGE = [&](int bu, int kk) {
    #pragma unroll
    for (int i = 0; i < 2; ++i) {
      int row = (tid + 256 * i) >> 2;
      gload_lds16(A  + (size_t)(rt * 128 + row) * HID_ + kk * 32 + u * 8,
                  a_l[bu] + (w * 64 + i * 256) * 8);
      gload_lds16(Wz + (size_t)(ct * 128 + row) * HID_ + kk * 32 + u * 8,
                  b_l[bu] + (w * 64 + i * 256) * 8);
    }
  };

  STAGE(0, 0);
  int cur = 0;
  for (int kk = 0; kk < 32; ++kk) {
    __syncthreads();            // drains vmcnt -> buf[cur] complete; orders prev reads
    if (kk + 1 < 32) STAGE(cur ^ 1, kk + 1);
    const u16* ab = a_l[cur];
    const u16* bb = b_l[cur];
    short8 af[4], bfr[4];
    #pragma unroll
    for (int i = 0; i < 4; ++i) {
      af[i]  = *(const short8*)(ab + (mq + i * 16 + l16) * 32 + cs);
      bfr[i] = *(const short8*)(bb + (nq + i * 16 + l16) * 32 + cs);
    }
    #pragma unroll
    for (int i = 0; i < 4; ++i)
      #pragma unroll
      for (int j = 0; j < 4; ++j)
        acc[i][j] = mfma_bf16(af[i], bfr[j], acc[i][j]);
    cur ^= 1;
  }

  #pragma unroll
  for (int j = 0; j < 4; ++j) {
    int col = ct * 128 + nq + j * 16 + l16;
    int hh = col >> 6, e = col & 63;
    float bb = bf2f(bias[hh * 64 + e]);
    #pragma unroll
    for (int i = 0; i < 4; ++i) {
      #pragma unroll
      for (int r = 0; r < 4; ++r) {
        int m = rt * 128 + mq + i * 16 + quad * 4 + r;
        int bidx = m >> 10, srow = m & 1023;
        O[(((size_t)(bidx * H_ + hh)) * S_ + srow) * DH_ + e] = f2bf(acc[i][j][r] + bb);
      }
    }
  }
}

// ---------------------------------------------------------------------------
// Fused attention, q-tile 64 x k-tile 64, 16 k-steps, 2 barriers each.
// This revision: the kernel is LDS-SLOT-bound (~69% of cycles are DS issue,
// by arithmetic from the PMC residual). One transformation cuts DS count:
// SWAPPED QK^T: s = mfma(K_frag, Q_frag) -> thread owns P[m0+l16][k =
// t*16+quad*4+r] (bitwise-identical values, transposed ownership). Derived:
//  - p_l stores: 16 scalar u16 -> 4x ds_write_b64 (4 contiguous k per t).
//    p_l LAYOUT UNCHANGED -> PV/indicator reads untouched.
//  - near tails: m is lane-private -> register-accumulate vlo/vhi over (t,r),
//    4x shfl_xor quad-reduce (was 128 shfl), 1 atomic per lane-row per kt.
//  - near interior: (m,dist) <-> unique k -> plain store, no atomic.
//  - far bias: per-lane scalar via preamble shfl-gather (same bf16 roundtrip).
// Plus V staging: lane=e gathers 16 k's (coalesced u16 global loads, idle
// VMEM pipe, L2-resident) -> 2x ds_write_b128 (was 16 scalar LDS writes).
// grid (16, 16, 4), block 256.
// ---------------------------------------------------------------------------
__global__ __launch_bounds__(256, 4) void attn_kernel(
    const u16* __restrict__ Q, const u16* __restrict__ K, const u16* __restrict__ V,
    const u16* __restrict__ conv, u16* __restrict__ Ox)
{
  // XCD-aware bijective swizzle of the flat block id (1024 blocks, 8 XCDs)
  const int bid = blockIdx.x + 16 * (blockIdx.y + 16 * blockIdx.z);
  const int nid = (bid & 7) * 128 + (bid >> 3);
  const int qt = nid & 15, h = (nid >> 4) & 15, b = nid >> 8;

  const int tid = threadIdx.x;
  const int lane = tid & 63, w = tid >> 6, quad = lane >> 4, l16 = lane & 15;
  const size_t base = ((size_t)(b * H_ + h)) * S_ * DH_;
  const u16* Kb = K + base;
  const u16* Vb = V + base;

  __shared__ __align__(16) char smem[40320];
  u16*   p_l    = (u16*)(smem);            // [64][72]; preamble: Q tile; epilogue: Bfull
  u16*   q_l    = p_l;                     // alias (dead after preamble)
  u16*   k_l    = (u16*)(smem + 9216);     // [64][72]; epilogue: relv^T [64 e][72]
  u16*   vt_l   = (u16*)(smem + 18432);    // [64 e][72] plain V^T (row e, col k)
  u16*   rq_l   = (u16*)(smem + 27648);    // [64][33] bf16 (near tiles only)
  float* bucket = (float*)(smem + 31872);  // [64][33]; preamble: relk_b u16 [48][72]
  u16*   rkb    = (u16*)(smem + 31872);

  // issue kt=0 K/V loads immediately; the whole preamble covers their latency
  uint4 kr0 = *(const uint4*)(Kb + (size_t)(tid >> 3) * DH_ + (tid & 7) * 8);
  uint4 kr1 = *(const uint4*)(Kb + (size_t)((tid >> 3) + 32) * DH_ + (tid & 7) * 8);
  __align__(16) u16 vtmp[16];
  #pragma unroll
  for (int j = 0; j < 16; ++j) vtmp[j] = Vb[(size_t)(w * 16 + j) * DH_ + lane];

  // preamble: stage Q tile + relk (B-layout rows, zero-padded to 48)
  #pragma unroll
  for (int i = 0; i < 2; ++i) {
    int idx = tid + 256 * i;
    int row = idx >> 3, c8 = (idx & 7) * 8;
    *(uint4*)(q_l + row * 72 + c8) =
        *(const uint4*)(Q + base + (size_t)(qt * 64 + row) * DH_ + c8);
  }
  const u16* relk = conv + OFF_RELK;
  for (int idx = tid; idx < 48 * 8; idx += 256) {
    int row = idx >> 3, c8 = (idx & 7) * 8;
    uint4 v = make_uint4(0, 0, 0, 0);
    if (row < NDIST) v = *(const uint4*)(relk + row * 64 + c8);
    *(uint4*)(rkb + row * 72 + c8) = v;
  }
  __syncthreads();

  const int m0 = w * 16;
  const int mrow = m0 + l16;            // this lane's q-row (swapped ownership)
  short8 qa0 = *(const short8*)(q_l + (m0 + l16) * 72 + quad * 8);
  short8 qa1 = *(const short8*)(q_l + (m0 + l16) * 72 + 32 + quad * 8);

  // RQ[m][d] = q[m,:] . relk[d,:]  (capture d=0 / d=32 accumulators)
  floatx4 c_d0 = {0.f,0.f,0.f,0.f}, c_d32 = {0.f,0.f,0.f,0.f};
  #pragma unroll
  for (int t3 = 0; t3 < 3; ++t3) {
    floatx4 c = {0.f,0.f,0.f,0.f};
    c = mfma_bf16(qa0, *(const short8*)(rkb + (t3 * 16 + l16) * 72 + quad * 8), c);
    c = mfma_bf16(qa1, *(const short8*)(rkb + (t3 * 16 + l16) * 72 + 32 + quad * 8), c);
    if (t3 == 0) c_d0 = c;
    if (t3 == 2) c_d32 = c;
    int d = t3 * 16 + l16;
    if (d < NDIST) {
      #pragma unroll
      for (int r = 0; r < 4; ++r) rq_l[(m0 + quad * 4 + r) * 33 + d] = f2bf(c[r]);
    }
  }
  // far-tile bias, per-lane scalar for m = mrow: RQ[m0+l16][0/32] lives in
  // lane (l16>>2)*16 reg (l16&3); gather + same bf16 round-trip, pre-scale.
  float rqs_lo, rqs_hi;
  {
    float t0 = 0.f, t2 = 0.f;
    #pragma unroll
    for (int r = 0; r < 4; ++r) {
      float a  = __shfl(c_d0[r],  (l16 >> 2) * 16, 64);
      float bb = __shfl(c_d32[r], (l16 >> 2) * 16, 64);
      if ((l16 & 3) == r) { t0 = a; t2 = bb; }
    }
    rqs_lo = bf2f(f2bf(t0)) * SCALE_;
    rqs_hi = bf2f(f2bf(t2)) * SCALE_;
  }
  __syncthreads();              // relk_b/q_l reads done -> regions become bucket/p_l
  for (int idx = tid; idx < 64 * 33; idx += 256) bucket[idx] = 0.f;

  floatx4 o[4], oi = {0.f,0.f,0.f,0.f};
  #pragma unroll
  for (int t = 0; t < 4; ++t) o[t] = (floatx4){0.f,0.f,0.f,0.f};

  for (int kt = 0; kt < 16; ++kt) {
    __syncthreads();            // prev iter LDS reads done (kt=0: bucket zero visible)
    // write-late: staged registers -> LDS (vmcnt wait forced by reg dataflow)
    *(uint4*)(k_l + (tid >> 3) * 72 + (tid & 7) * 8) = kr0;
    *(uint4*)(k_l + ((tid >> 3) + 32) * 72 + (tid & 7) * 8) = kr1;
    *(uint4*)(vt_l + lane * 72 + w * 16)     = *(const uint4*)(vtmp);
    *(uint4*)(vt_l + lane * 72 + w * 16 + 8) = *(const uint4*)(vtmp + 8);
    __syncthreads();
    // issue-early: next tile's loads fly under the whole compute phase
    if (kt < 15) {
      const size_t kb = (size_t)((kt + 1) * 64);
      kr0 = *(const uint4*)(Kb + (kb + (tid >> 3)) * DH_ + (tid & 7) * 8);
      kr1 = *(const uint4*)(Kb + (kb + (tid >> 3) + 32) * DH_ + (tid & 7) * 8);
      #pragma unroll
      for (int j = 0; j < 16; ++j) vtmp[j] = Vb[(kb + w * 16 + j) * DH_ + lane];
    }

    const int dkt = kt - qt;
    const bool near = (dkt >= -1) && (dkt <= 1);
    float vlo = 0.f, vhi = 0.f;

    #pragma unroll
    for (int t = 0; t < 4; ++t) {
      floatx4 s = {0.f,0.f,0.f,0.f};
      short8 ka0 = *(const short8*)(k_l + (t * 16 + l16) * 72 + quad * 8);
      short8 ka1 = *(const short8*)(k_l + (t * 16 + l16) * 72 + 32 + quad * 8);
      s = mfma_bf16(ka0, qa0, s);   // swapped: C[k][m], col = l16 = m - m0
      s = mfma_bf16(ka1, qa1, s);
      // s[r] = S[k = kt*64 + t*16 + quad*4 + r][qt*64 + mrow]
      __align__(8) u16 pk[4];
      if (near) {
        #pragma unroll
        for (int r = 0; r < 4; ++r) {
          int delta = dkt * 64 + t * 16 + quad * 4 + r - mrow;
          int dist = (delta < -16 ? -16 : (delta > 16 ? 16 : delta)) + 16;
          float logit = (s[r] + bf2f(rq_l[mrow * 33 + dist])) * SCALE_;
          u16 pu = f2bf(__expf(fminf(logit, 30.f)));
          pk[r] = pu;
          float pv = bf2f(pu);
          if (dist == 0)       vlo += pv;
          else if (dist == 32) vhi += pv;
          else                 bucket[mrow * 33 + dist] = pv;  // unique writer
        }
      } else {
        float rqs = (dkt < 0) ? rqs_lo : rqs_hi;
        #pragma unroll
        for (int r = 0; r < 4; ++r) {
          float logit = fmaf(s[r], SCALE_, rqs);
          pk[r] = f2bf(__expf(fminf(logit, 30.f)));
        }
      }
      *(uint2*)(p_l + mrow * 72 + t * 16 + quad * 4) = *(const uint2*)pk;
    }
    if (near) {
      vlo += __shfl_xor(vlo, 16); vlo += __shfl_xor(vlo, 32);
      vhi += __shfl_xor(vhi, 16); vhi += __shfl_xor(vhi, 32);
      if (quad == 0) {
        if (vlo != 0.f) atomicAdd(&bucket[mrow * 33 + 0], vlo);
        if (vhi != 0.f) atomicAdd(&bucket[mrow * 33 + 32], vhi);
      }
    }

    // PV + far-tile indicator row-sums (same-wave P round-trip, no barrier)
    u16 iv = ((l16 == 0 && dkt <= -2) || (l16 == 1 && dkt >= 2)) ? (u16)0x3F80 : (u16)0;
    short8 ib;
    #pragma unroll
    for (int j = 0; j < 8; ++j) ib[j] = (short)iv;
    short8 pa0 = *(const short8*)(p_l + (m0 + l16) * 72 + quad * 8);
    short8 pa1 = *(const short8*)(p_l + (m0 + l16) * 72 + 32 + quad * 8);
    oi = mfma_bf16(pa0, ib, oi);
    oi = mfma_bf16(pa1, ib, oi);
    #pragma unroll
    for (int t = 0; t < 4; ++t) {
      int e = t * 16 + l16;
      short8 vb0 = *(const short8*)(vt_l + e * 72 + quad * 8);
      short8 vb1 = *(const short8*)(vt_l + e * 72 + 32 + quad * 8);
      o[t] = mfma_bf16(pa0, vb0, o[t]);
      o[t] = mfma_bf16(pa1, vb1, o[t]);
    }
  }

  __syncthreads();              // loop LDS use + atomics done
  // fold far sums (s_lo at col0, s_hi at col1 of oi) into bucket
  if (l16 == 0) {
    #pragma unroll
    for (int r = 0; r < 4; ++r) bucket[(m0 + quad * 4 + r) * 33 + 0] += oi[r];
  } else if (l16 == 1) {
    #pragma unroll
    for (int r = 0; r < 4; ++r) bucket[(m0 + quad * 4 + r) * 33 + 32] += oi[r];
  }
  __syncthreads();

  u16* rvT = k_l;               // relv^T [64 e][72]
  u16* Bf  = p_l;               // Bfull bf16 [64 m][72]
  for (int idx = tid; idx < 576; idx += 256) {
    ((uint4*)rvT)[idx] = make_uint4(0, 0, 0, 0);
    ((uint4*)Bf)[idx]  = make_uint4(0, 0, 0, 0);
  }
  __syncthreads();
  const u16* relv = conv + OFF_RELV;
  for (int idx = tid; idx < NDIST * 64; idx += 256) {
    int d = idx >> 6, e = idx & 63;
    rvT[e * 72 + d] = relv[idx];
  }
  for (int idx = tid; idx < 64 * NDIST; idx += 256) {
    int m = idx / NDIST, d = idx - m * NDIST;
    Bf[m * 72 + d] = f2bf(bucket[m * 33 + d]);
  }
  __syncthreads();

  // o += Bfull @ relv
  short8 ba0 = *(const short8*)(Bf + (m0 + l16) * 72 + quad * 8);
  short8 ba1 = *(const short8*)(Bf + (m0 + l16) * 72 + 32 + quad * 8);
  #pragma unroll
  for (int t = 0; t < 4; ++t) {
    short8 rb0 = *(const short8*)(rvT + (t * 16 + l16) * 72 + quad * 8);
    short8 rb1 = *(const short8*)(rvT + (t * 16 + l16) * 72 + 32 + quad * 8);
    o[t] = mfma_bf16(ba0, rb0, o[t]);
    o[t] = mfma_bf16(ba1, rb1, o[t]);
  }

  float rl[4];
  #pragma unroll
  for (int r = 0; r < 4; ++r) {
    int m = m0 + quad * 4 + r;
    float s = 0.f;
    #pragma unroll
    for (int d = 0; d < NDIST; ++d) s += bucket[m * 33 + d];
    rl[r] = 1.f / s;
  }

  #pragma unroll
  for (int t = 0; t < 4; ++t) {
    int e = t * 16 + l16;
    #pragma unroll
    for (int r = 0; r < 4; ++r) {
      int srow = qt * 64 + m0 + quad * 4 + r;
      Ox[((size_t)(b * S_ + srow)) * HID_ + h * 64 + e] = f2bf(o[t][r] * rl[r]);
    }
  }
}

// ---------------------------------------------------------------------------
// fc: out = X @ fcW^T + b. X bf16 [4096][1024] (ws), fcW k-contiguous.
// Same dbuf + 1-barrier + chunk-XOR-swizzle structure as proj, plus XCD
// swizzle. 128x128 tile, BK=32, grid (32, 8), block 256. Dual-dtype output.
// ---------------------------------------------------------------------------
__global__ __launch_bounds__(256, 3) void fc_kernel(
    const u16* __restrict__ X, const u16* __restrict__ conv,
    const int* __restrict__ flag, void* __restrict__ outv)
{
  const u16* Wf  = conv + OFF_FCW;
  const u16* bfc = conv + OFF_FCB;
  // XCD-bijective remap: XCD x <- ct = x, rt = bid/8
  const int bid = blockIdx.x + 32 * blockIdx.y;     // [0,256)
  const int ct = bid & 7, rt = bid >> 3;
  const int tid = threadIdx.x, lane = tid & 63, w = tid >> 6, quad = lane >> 4, l16 = lane & 15;
  const int isf = *flag;

  __shared__ __align__(16) u16 a_l[2][128 * 32];
  __shared__ __align__(16) u16 b_l[2][128 * 32];

  floatx4 acc[4][4];
  #pragma unroll
  for (int i = 0; i < 4; ++i)
    #pragma unroll
    for (int j = 0; j < 4; ++j) acc[i][j] = (floatx4){0.f,0.f,0.f,0.f};

  const int mq = (w & 1) * 64, nq = (w >> 1) * 64;
  const int u = (lane & 3) ^ ((lane >> 3) & 3);
  const int cs = (quad ^ ((l16 >> 1) & 3)) * 8;

  auto STAGE = [&](int bu, int kk) {
    #pragma unroll
    for (int i = 0; i < 2; ++i) {
      int row = (tid + 256 * i) >> 2;
      gload_lds16(X  + (size_t)(rt * 128 + row) * HID_ + kk * 32 + u * 8,
                  a_l[bu] + (w * 64 + i * 256) * 8);
      gload_lds16(Wf + (size_t)(ct * 128 + row) * HID_ + kk * 32 + u * 8,
                  b_l[bu] + (w * 64 + i * 256) * 8);
    }
  };

  STAGE(0, 0);
  int cur = 0;
  for (int kk = 0; kk < 32; ++kk) {
    __syncthreads();
    if (kk + 1 < 32) STAGE(cur ^ 1, kk + 1);
    const u16* ab = a_l[cur];
    const u16* bb = b_l[cur];
    short8 af[4], bfr[4];
    #pragma unroll
    for (int i = 0; i < 4; ++i) {
      af[i]  = *(const short8*)(ab + (mq + i * 16 + l16) * 32 + cs);
      bfr[i] = *(const short8*)(bb + (nq + i * 16 + l16) * 32 + cs);
    }
    #pragma unroll
    for (int i = 0; i < 4; ++i)
      #pragma unroll
      for (int j = 0; j < 4; ++j)
        acc[i][j] = mfma_bf16(af[i], bfr[j], acc[i][j]);
    cur ^= 1;
  }

  #pragma unroll
  for (int j = 0; j < 4; ++j) {
    int col = ct * 128 + nq + j * 16 + l16;
    float bb = bf2f(bfc[col]);
    #pragma unroll
    for (int i = 0; i < 4; ++i) {
      #pragma unroll
      for (int r = 0; r < 4; ++r) {
        int m = rt * 128 + mq + i * 16 + quad * 4 + r;
        float val = acc[i][j][r] + bb;
        size_t idx = (size_t)m * HID_ + col;
        if (isf) ((float*)outv)[idx] = val;
        else     ((u16*)outv)[idx]   = f2bf(val);
      }
    }
  }
}

extern "C" void kernel_launch(void* const* d_in, const int* in_sizes, int n_in,
                              void* d_out, int out_size, void* d_ws, size_t ws_size,
                              hipStream_t stream) {
  int* flag = (int*)d_ws;
  u16* conv = (u16*)((char*)d_ws + 16);
  u16* wt   = conv + CONV_TOT;                 // 3*16*64*1024 = 3,145,728
  u16* qw   = wt + 3145728;
  u16* kw   = qw + 4194304;
  u16* vw   = kw + 4194304;
  u16* xw   = vw + 4194304;
  // bf16 copies of Q/K/V inputs. qc overlays xw: proj reads qc; attn writes
  // xw only after proj completes (stream-ordered). kc/vc extend the ws.
  u16* qc   = xw;
  u16* kc   = xw + 4194304;
  u16* vc   = kc + 4194304;

  detect_kernel<<<1, 256, 0, stream>>>((const u16*)d_in[0], flag);

  SrcPtrs sp;
  sp.p[0] = d_in[4];  sp.p[1] = d_in[6];  sp.p[2] = d_in[8];
  sp.p[3] = d_in[9];  sp.p[4] = d_in[10]; sp.p[5] = d_in[11]; sp.p[6] = d_in[12];
  convert_kernel<<<1034, 256, 0, stream>>>(sp, flag, conv);
  qkvconv_kernel<<<2048, 256, 0, stream>>>(d_in[0], d_in[1], d_in[2], flag, qc, kc, vc);

  wtrans_kernel<<<dim3(16, 16, 3), 256, 0, stream>>>(d_in[3], d_in[5], d_in[7], flag, wt);
  proj_kernel<<<dim3(32, 8, 3), 256, 0, stream>>>(qc, kc, vc, wt, conv, qw, kw, vw);
  attn_kernel<<<dim3(16, 16, 4), 256, 0, stream>>>(qw, kw, vw, conv, xw);
  fc_kernel<<<dim3(32, 8), 256, 0, stream>>>(xw, conv, flag, (u16*)d_out);
}